// Round 1
// baseline (281.041 us; speedup 1.0000x reference)
//
#include <hip/hip_runtime.h>
#include <hip/hip_bf16.h>

#define IN_F   4096
#define OUT_F  11008
#define GS     128
#define NGRP   32      // IN_F / GS
#define M      32
#define TILE_N 512
#define NT     22      // ceil(OUT_F / TILE_N)

__device__ __forceinline__ float bf16r(float v) {
    return __bfloat162float(__float2bfloat16(v));
}

// Kernel 1: per-(group, n-tile) partial GEMM. Partials stored as bf16 in ws:
// part[((g*M)+m)*OUT_F + n]
__global__ __launch_bounds__(256) void qk_main(
    const float* __restrict__ x, const int* __restrict__ qw,
    const int* __restrict__ qz, const float* __restrict__ sc,
    __hip_bfloat16* __restrict__ part)
{
    const int g  = blockIdx.y;          // quant group = k-split
    const int tx = threadIdx.x;

    __shared__ float xs[GS][M];         // [kk][m], bf16-rounded x^T slice
    // stage x: i = kk*32 + m -> LDS word index == i -> conflict-free writes.
    // Global reads are an m-major gather; x is tiny (512 KB) and L2-resident.
    #pragma unroll
    for (int i = tx; i < GS * M; i += 256) {
        int m  = i & (M - 1);
        int kk = i >> 5;
        xs[kk][m] = bf16r(x[m * IN_F + g * GS + kk]);
    }

    int n0  = blockIdx.x * TILE_N + tx * 2;        // even
    int n0c = n0 > OUT_F - 2 ? OUT_F - 2 : n0;     // clamp for safe loads

    const float2 scv = *(const float2*)(sc + (size_t)g * OUT_F + n0c);
    const int2   qzv = *(const int2*)  (qz + (size_t)g * OUT_F + n0c);
    float s0 = bf16r(scv.x), s1 = bf16r(scv.y);
    float o0 = -(float)qzv.x * s0;
    float o1 = -(float)qzv.y * s1;

    float acc0[M], acc1[M];
    #pragma unroll
    for (int m = 0; m < M; ++m) { acc0[m] = 0.f; acc1[m] = 0.f; }

    const int* qp = qw + (size_t)g * GS * OUT_F + n0c;

    __syncthreads();

    #pragma unroll 8
    for (int kk = 0; kk < GS; ++kk) {
        int2 q = *(const int2*)qp;
        qp += OUT_F;
        float w0 = (float)q.x * s0 + o0;   // == (q - z) * s exactly
        float w1 = (float)q.y * s1 + o1;
        const float4* xv = (const float4*)&xs[kk][0];
        #pragma unroll
        for (int j = 0; j < M / 4; ++j) {
            float4 xx = xv[j];
            acc0[4*j+0] += xx.x * w0;  acc1[4*j+0] += xx.x * w1;
            acc0[4*j+1] += xx.y * w0;  acc1[4*j+1] += xx.y * w1;
            acc0[4*j+2] += xx.z * w0;  acc1[4*j+2] += xx.z * w1;
            acc0[4*j+3] += xx.w * w0;  acc1[4*j+3] += xx.w * w1;
        }
    }

    if (n0 < OUT_F) {   // n0 even, OUT_F even -> n0+1 also valid
        __hip_bfloat16* pp = part + (size_t)g * M * OUT_F + n0;
        #pragma unroll
        for (int m = 0; m < M; ++m) {
            __hip_bfloat162 hv;
            hv.x = __float2bfloat16(acc0[m]);
            hv.y = __float2bfloat16(acc1[m]);
            *(__hip_bfloat162*)(pp + (size_t)m * OUT_F) = hv;
        }
    }
}

// Kernel 2: reduce 32 bf16 partials + bias -> f32 out
__global__ __launch_bounds__(256) void qk_red(
    const __hip_bfloat16* __restrict__ part,
    const float* __restrict__ bias, float* __restrict__ out)
{
    const int m  = blockIdx.y;
    const int n0 = (blockIdx.x * 256 + threadIdx.x) * 2;
    if (n0 >= OUT_F) return;
    float a0 = 0.f, a1 = 0.f;
    #pragma unroll
    for (int gi = 0; gi < NGRP; ++gi) {
        __hip_bfloat162 v = *(const __hip_bfloat162*)(
            part + ((size_t)gi * M + m) * OUT_F + n0);
        a0 += __bfloat162float(v.x);
        a1 += __bfloat162float(v.y);
    }
    float2 r;
    r.x = a0 + bf16r(bias[n0]);
    r.y = a1 + bf16r(bias[n0 + 1]);
    *(float2*)(out + (size_t)m * OUT_F + n0) = r;
}

extern "C" void kernel_launch(void* const* d_in, const int* in_sizes, int n_in,
                              void* d_out, int out_size, void* d_ws, size_t ws_size,
                              hipStream_t stream) {
    const float* x    = (const float*)d_in[0];
    const int*   qw   = (const int*)  d_in[1];
    const int*   qz   = (const int*)  d_in[2];
    const float* sc   = (const float*)d_in[3];
    const float* bias = (const float*)d_in[4];
    float* out = (float*)d_out;
    __hip_bfloat16* part = (__hip_bfloat16*)d_ws;  // NGRP*M*OUT_F bf16 = 22.5 MB

    dim3 g1(NT, NGRP, 1);
    qk_main<<<g1, dim3(256, 1, 1), 0, stream>>>(x, qw, qz, sc, part);

    dim3 g2((OUT_F / 2 + 255) / 256, M, 1);
    qk_red<<<g2, dim3(256, 1, 1), 0, stream>>>(part, bias, out);
}

// Round 2
// 280.930 us; speedup vs baseline: 1.0004x; 1.0004x over previous
//
#include <hip/hip_runtime.h>
#include <hip/hip_bf16.h>

#define IN_F   4096
#define OUT_F  11008
#define GS     128
#define M      32
#define KCH    256       // k-rows per block = 2 quant groups
#define NSPLIT 16        // IN_F / KCH
#define TILE_N 512
#define NT     22        // ceil(OUT_F / TILE_N), last tile clamped

__device__ __forceinline__ float bf16r(float v) {
    return __bfloat162float(__float2bfloat16(v));
}

// Kernel 1: per-(k-split, n-tile) partial GEMM.
// part[((split*M)+m)*OUT_F + n], bf16.
__global__ __launch_bounds__(256) void qk_main(
    const float* __restrict__ x, const int* __restrict__ qw,
    const int* __restrict__ qz, const float* __restrict__ sc,
    __hip_bfloat16* __restrict__ part)
{
    const int ks = blockIdx.y;          // k-split (2 groups)
    const int tx = threadIdx.x;

    __shared__ float xs[KCH][M];        // [kk][m], bf16-rounded x^T slice, 32 KB
    #pragma unroll
    for (int i = tx; i < KCH * M; i += 256) {
        int m  = i & (M - 1);
        int kk = i >> 5;
        xs[kk][m] = bf16r(x[m * IN_F + ks * KCH + kk]);
    }

    int n0  = blockIdx.x * TILE_N + tx * 2;        // even
    int n0c = n0 > OUT_F - 2 ? OUT_F - 2 : n0;     // clamp for safe loads

    const int g0 = ks * 2;
    float2 sa = *(const float2*)(sc + (size_t)g0       * OUT_F + n0c);
    float2 sb = *(const float2*)(sc + (size_t)(g0 + 1) * OUT_F + n0c);
    int2   za = *(const int2*)  (qz + (size_t)g0       * OUT_F + n0c);
    int2   zb = *(const int2*)  (qz + (size_t)(g0 + 1) * OUT_F + n0c);
    float s0a = bf16r(sa.x), s1a = bf16r(sa.y);
    float s0b = bf16r(sb.x), s1b = bf16r(sb.y);
    float o0a = -(float)za.x * s0a, o1a = -(float)za.y * s1a;
    float o0b = -(float)zb.x * s0b, o1b = -(float)zb.y * s1b;

    float acc0[M], acc1[M];
    #pragma unroll
    for (int m = 0; m < M; ++m) { acc0[m] = 0.f; acc1[m] = 0.f; }

    const int* qbase = qw + (size_t)ks * KCH * OUT_F + n0c;

    // Explicit ping-pong prefetch: 8 int2 (64 B/lane) always in flight.
    // Statically-named buffers (no runtime-indexed register arrays).
    int2 qA[8], qB[8];
    #pragma unroll
    for (int j = 0; j < 8; ++j)
        qA[j] = *(const int2*)(qbase + (size_t)j * OUT_F);

    __syncthreads();

    // 16 iterations; iteration c handles chunk 2c (qA) and 2c+1 (qB),
    // 8 k-rows each. Chunks 0-15 use group g0, 16-31 use g0+1, so within
    // an iteration both chunks share the same group (c<8 <=> group g0).
    for (int c = 0; c < 16; ++c) {
        float cs0 = c < 8 ? s0a : s0b;
        float cs1 = c < 8 ? s1a : s1b;
        float co0 = c < 8 ? o0a : o0b;
        float co1 = c < 8 ? o1a : o1b;

        int rB = (2 * c + 1) * 8;
        #pragma unroll
        for (int j = 0; j < 8; ++j)
            qB[j] = *(const int2*)(qbase + (size_t)(rB + j) * OUT_F);

        {   // compute chunk 2c from qA: k-rows 16c .. 16c+7
            int kb = 16 * c;
            #pragma unroll
            for (int j = 0; j < 8; ++j) {
                float w0 = (float)qA[j].x * cs0 + co0;   // == (q-z)*s exactly
                float w1 = (float)qA[j].y * cs1 + co1;
                const float4* xv = (const float4*)&xs[kb + j][0];
                #pragma unroll
                for (int q4 = 0; q4 < M / 4; ++q4) {
                    float4 xx = xv[q4];
                    acc0[4*q4+0] += xx.x * w0;  acc1[4*q4+0] += xx.x * w1;
                    acc0[4*q4+1] += xx.y * w0;  acc1[4*q4+1] += xx.y * w1;
                    acc0[4*q4+2] += xx.z * w0;  acc1[4*q4+2] += xx.z * w1;
                    acc0[4*q4+3] += xx.w * w0;  acc1[4*q4+3] += xx.w * w1;
                }
            }
        }

        int rA = (2 * c + 2) * 8;                 // next iteration's qA chunk
        if (rA > KCH - 8) rA = KCH - 8;           // clamp (dead data, c==15)
        #pragma unroll
        for (int j = 0; j < 8; ++j)
            qA[j] = *(const int2*)(qbase + (size_t)(rA + j) * OUT_F);

        {   // compute chunk 2c+1 from qB: k-rows 16c+8 .. 16c+15
            int kb = 16 * c + 8;
            #pragma unroll
            for (int j = 0; j < 8; ++j) {
                float w0 = (float)qB[j].x * cs0 + co0;
                float w1 = (float)qB[j].y * cs1 + co1;
                const float4* xv = (const float4*)&xs[kb + j][0];
                #pragma unroll
                for (int q4 = 0; q4 < M / 4; ++q4) {
                    float4 xx = xv[q4];
                    acc0[4*q4+0] += xx.x * w0;  acc1[4*q4+0] += xx.x * w1;
                    acc0[4*q4+1] += xx.y * w0;  acc1[4*q4+1] += xx.y * w1;
                    acc0[4*q4+2] += xx.z * w0;  acc1[4*q4+2] += xx.z * w1;
                    acc0[4*q4+3] += xx.w * w0;  acc1[4*q4+3] += xx.w * w1;
                }
            }
        }
    }

    if (n0 < OUT_F) {   // n0 even, OUT_F even -> n0+1 also valid
        __hip_bfloat16* pp = part + (size_t)ks * M * OUT_F + n0;
        #pragma unroll
        for (int m = 0; m < M; ++m) {
            __hip_bfloat162 hv;
            hv.x = __float2bfloat16(acc0[m]);
            hv.y = __float2bfloat16(acc1[m]);
            *(__hip_bfloat162*)(pp + (size_t)m * OUT_F) = hv;
        }
    }
}

// Kernel 2: reduce NSPLIT bf16 partials + bias -> f32 out
__global__ __launch_bounds__(256) void qk_red(
    const __hip_bfloat16* __restrict__ part,
    const float* __restrict__ bias, float* __restrict__ out)
{
    const int m  = blockIdx.y;
    const int n0 = (blockIdx.x * 256 + threadIdx.x) * 2;
    if (n0 >= OUT_F) return;
    float a0 = 0.f, a1 = 0.f;
    #pragma unroll
    for (int s = 0; s < NSPLIT; ++s) {
        __hip_bfloat162 v = *(const __hip_bfloat162*)(
            part + ((size_t)s * M + m) * OUT_F + n0);
        a0 += __bfloat162float(v.x);
        a1 += __bfloat162float(v.y);
    }
    float2 r;
    r.x = a0 + bf16r(bias[n0]);
    r.y = a1 + bf16r(bias[n0 + 1]);
    *(float2*)(out + (size_t)m * OUT_F + n0) = r;
}

extern "C" void kernel_launch(void* const* d_in, const int* in_sizes, int n_in,
                              void* d_out, int out_size, void* d_ws, size_t ws_size,
                              hipStream_t stream) {
    const float* x    = (const float*)d_in[0];
    const int*   qw   = (const int*)  d_in[1];
    const int*   qz   = (const int*)  d_in[2];
    const float* sc   = (const float*)d_in[3];
    const float* bias = (const float*)d_in[4];
    float* out = (float*)d_out;
    __hip_bfloat16* part = (__hip_bfloat16*)d_ws;  // NSPLIT*M*OUT_F bf16 = 11.3 MB

    dim3 g1(NT, NSPLIT, 1);
    qk_main<<<g1, dim3(256, 1, 1), 0, stream>>>(x, qw, qz, sc, part);

    dim3 g2((OUT_F / 2 + 255) / 256, M, 1);
    qk_red<<<g2, dim3(256, 1, 1), 0, stream>>>(part, bias, out);
}

// Round 3
// 270.505 us; speedup vs baseline: 1.0390x; 1.0385x over previous
//
#include <hip/hip_runtime.h>
#include <hip/hip_bf16.h>

#define IN_F   4096
#define OUT_F  11008
#define GS     128
#define M      32
#define NSPLIT 32        // IN_F / GS, one quant group per k-split
#define TILE_N 512
#define NT     22        // ceil(OUT_F / TILE_N), last tile clamped

__device__ __forceinline__ float bf16r(float v) {
    return __bfloat162float(__float2bfloat16(v));
}

// Kernel 0: pre-round x to bf16 and transpose to xt[k][m] (rows of 128 B).
// xt lives in ws; re-built every launch (ws is re-poisoned by the harness).
__global__ __launch_bounds__(256) void qk_prep(
    const float* __restrict__ x, float* __restrict__ xt)
{
    int t = blockIdx.x * 256 + threadIdx.x;   // 0 .. IN_F*M-1
    int m = t & (M - 1);
    int k = t >> 5;
    xt[t] = bf16r(x[m * IN_F + k]);           // xt[k*32+m]
}

// Kernel 1: per-(group, n-tile) partial GEMM; partials bf16 in ws.
// x comes from xt via wave-uniform loads (scalarized to s_load) -> no LDS.
__global__ __launch_bounds__(256) void qk_main(
    const float* __restrict__ xt, const int* __restrict__ qw,
    const int* __restrict__ qz, const float* __restrict__ sc,
    __hip_bfloat16* __restrict__ part)
{
    const int g  = blockIdx.y;          // quant group = k-split
    const int tx = threadIdx.x;

    int n0  = blockIdx.x * TILE_N + tx * 2;        // even
    int n0c = n0 > OUT_F - 2 ? OUT_F - 2 : n0;     // clamp for safe loads

    const float2 scv = *(const float2*)(sc + (size_t)g * OUT_F + n0c);
    const int2   qzv = *(const int2*)  (qz + (size_t)g * OUT_F + n0c);
    float s0 = bf16r(scv.x), s1 = bf16r(scv.y);
    float o0 = -(float)qzv.x * s0;      // w = q*s + (-z*s) == (q-z)*s exactly
    float o1 = -(float)qzv.y * s1;

    float acc0[M], acc1[M];
    #pragma unroll
    for (int m = 0; m < M; ++m) { acc0[m] = 0.f; acc1[m] = 0.f; }

    const int*   qp = qw + (size_t)g * GS * OUT_F + n0c;
    const float* xr = xt + (size_t)g * GS * M;     // wave-uniform base

    #pragma unroll 8
    for (int kk = 0; kk < GS; ++kk) {
        int2 q = *(const int2*)qp;
        qp += OUT_F;
        float w0 = (float)q.x * s0 + o0;
        float w1 = (float)q.y * s1 + o1;
        const float4* xv = (const float4*)(xr + kk * M);  // uniform address
        #pragma unroll
        for (int j = 0; j < M / 4; ++j) {
            float4 xx = xv[j];
            acc0[4*j+0] += xx.x * w0;  acc1[4*j+0] += xx.x * w1;
            acc0[4*j+1] += xx.y * w0;  acc1[4*j+1] += xx.y * w1;
            acc0[4*j+2] += xx.z * w0;  acc1[4*j+2] += xx.z * w1;
            acc0[4*j+3] += xx.w * w0;  acc1[4*j+3] += xx.w * w1;
        }
    }

    if (n0 < OUT_F) {   // n0 even, OUT_F even -> n0+1 also valid
        __hip_bfloat16* pp = part + (size_t)g * M * OUT_F + n0;
        #pragma unroll
        for (int m = 0; m < M; ++m) {
            __hip_bfloat162 hv;
            hv.x = __float2bfloat16(acc0[m]);
            hv.y = __float2bfloat16(acc1[m]);
            *(__hip_bfloat162*)(pp + (size_t)m * OUT_F) = hv;
        }
    }
}

// Kernel 2: reduce NSPLIT bf16 partials + bias -> f32 out
__global__ __launch_bounds__(256) void qk_red(
    const __hip_bfloat16* __restrict__ part,
    const float* __restrict__ bias, float* __restrict__ out)
{
    const int m  = blockIdx.y;
    const int n0 = (blockIdx.x * 256 + threadIdx.x) * 2;
    if (n0 >= OUT_F) return;
    float a0 = 0.f, a1 = 0.f;
    #pragma unroll
    for (int s = 0; s < NSPLIT; ++s) {
        __hip_bfloat162 v = *(const __hip_bfloat162*)(
            part + ((size_t)s * M + m) * OUT_F + n0);
        a0 += __bfloat162float(v.x);
        a1 += __bfloat162float(v.y);
    }
    float2 r;
    r.x = a0 + bf16r(bias[n0]);
    r.y = a1 + bf16r(bias[n0 + 1]);
    *(float2*)(out + (size_t)m * OUT_F + n0) = r;
}

extern "C" void kernel_launch(void* const* d_in, const int* in_sizes, int n_in,
                              void* d_out, int out_size, void* d_ws, size_t ws_size,
                              hipStream_t stream) {
    const float* x    = (const float*)d_in[0];
    const int*   qw   = (const int*)  d_in[1];
    const int*   qz   = (const int*)  d_in[2];
    const float* sc   = (const float*)d_in[3];
    const float* bias = (const float*)d_in[4];
    float* out = (float*)d_out;

    float* xt = (float*)d_ws;                                  // 512 KB
    __hip_bfloat16* part = (__hip_bfloat16*)((char*)d_ws + (size_t)IN_F * M * 4);
    // part: NSPLIT*M*OUT_F bf16 = 22.5 MB

    qk_prep<<<IN_F * M / 256, 256, 0, stream>>>(x, xt);

    dim3 g1(NT, NSPLIT, 1);
    qk_main<<<g1, dim3(256, 1, 1), 0, stream>>>(xt, qw, qz, sc, part);

    dim3 g2((OUT_F / 2 + 255) / 256, M, 1);
    qk_red<<<g2, dim3(256, 1, 1), 0, stream>>>(part, bias, out);
}